// Round 2
// baseline (321.059 us; speedup 1.0000x reference)
//
#include <hip/hip_runtime.h>
#include <hip/hip_bf16.h>
#include <math.h>

#define Nn 50000
#define Ee 800000
#define Cc 16
#define Mm 32
#define Gg 8
#define CAP 64            // per-node edge-slot capacity (max deg ~35 for this input)

#define FILLB 1536        // fill blocks (192 per XCD group)
#define L0B 400           // layer0 blocks (grid-strided)
#define NAB 2048          // aggr blocks (4 waves each)
#define NPG (Nn / 8)      // 6250 src nodes per XCD group

// ---------------------------------------------------------------------------
// helpers
// ---------------------------------------------------------------------------
__device__ __forceinline__ float ldin(const void* p, int idx, int isbf) {
    if (isbf) return __bfloat162float(((const __hip_bfloat16*)p)[idx]);
    return ((const float*)p)[idx];
}
__device__ __forceinline__ void stout(void* p, size_t idx, float v, int isbf) {
    if (isbf) ((__hip_bfloat16*)p)[idx] = __float2bfloat16(v);
    else ((float*)p)[idx] = v;
}
__device__ __forceinline__ unsigned short f2bf(float f) {    // RNE f32 -> bf16 bits
    unsigned u = __float_as_uint(f);
    return (unsigned short)((u + 0x7FFFu + ((u >> 16) & 1u)) >> 16);
}
__device__ __forceinline__ float bflo(unsigned v) { return __uint_as_float(v << 16); }
__device__ __forceinline__ float bfhi(unsigned v) { return __uint_as_float(v & 0xffff0000u); }

__device__ __forceinline__ int detect_bf16(const void* B0, int tid, int* sflag) {
    if (tid < 64) {
        unsigned wv = ((const unsigned*)B0)[tid];
        unsigned ex = (wv >> 7) & 0xFFu;
        unsigned long long m = __ballot(ex >= 120u && ex <= 130u);
        if (tid == 0) *sflag = (__popcll(m) >= 48) ? 1 : 0;
    }
    __syncthreads();
    return *sflag;
}

// in-place softmax of one LDS column: entries base + k*stride, k in [0,cnt)
__device__ __forceinline__ void sm_col(float* a, int base, int stride, int cnt) {
    float mx = -1e30f;
    for (int k = 0; k < cnt; ++k) mx = fmaxf(mx, a[base + k * stride]);
    float s = 0.f;
    for (int k = 0; k < cnt; ++k) {
        float e = __expf(a[base + k * stride] - mx);
        a[base + k * stride] = e;
        s += e;
    }
    float inv = 1.0f / s;
    for (int k = 0; k < cnt; ++k) a[base + k * stride] *= inv;
}

// ---------------------------------------------------------------------------
// Kernel 1: blocks [0,FILLB)           = bucketed fill+count
//           blocks [FILLB,FILLB+L0B)   = layer0 (self-staged B0/Pi in sh[])
//           block  FILLB+L0B           = layer-1 table producer + zero-row
// R12 fill change: deg padded to ONE counter per 64B line (stride 16 ints).
// Probes the per-line atomic-serialization hypothesis (256 atomics/line -> 16).
// ---------------------------------------------------------------------------
__global__ void fill_layer0(const int* __restrict__ ei,
                            const int* __restrict__ x,
                            const void* __restrict__ B0,
                            const void* __restrict__ Pi,
                            const void* __restrict__ B1,
                            const void* __restrict__ Q,
                            int* __restrict__ deg,          // padded: deg[n*16]
                            int* __restrict__ sorted_dst,
                            unsigned short* __restrict__ post0,
                            float* __restrict__ smB1ws,     // [i][m][g] fp32
                            float* __restrict__ smQgws,     // [g][i][l] fp32
                            int* __restrict__ flag_ws,
                            void* __restrict__ out) {
    int b = blockIdx.x;
    if (b < FILLB) {   // ---- fill: group owns contiguous node range (XCD-local) ----
        int grp = b & 7, sub = b >> 3;
        int lo = grp * NPG, hi = lo + NPG;
        const int NQ = Ee / 4;                      // 200000 int4 quads of src
        const int stride = (FILLB >> 3) * 256;      // 49152 threads per group
        const int4* ei4 = (const int4*)ei;
        int ps = -1, pd = 0;                        // pending (src,dst) pair
        for (int q = sub * 256 + threadIdx.x; q < NQ; q += stride) {
            int4 sv = ei4[q];
#pragma unroll
            for (int k = 0; k < 4; ++k) {
                int s = (k == 0) ? sv.x : (k == 1) ? sv.y : (k == 2) ? sv.z : sv.w;
                if (s >= lo && s < hi) {
                    int dv = ei[Ee + 4 * q + k];
                    if (ps < 0) { ps = s; pd = dv; }
                    else {
                        int p0 = atomicAdd(&deg[ps << 4], 1);   // padded counters
                        int p1 = atomicAdd(&deg[s << 4], 1);
                        if (p0 < CAP) sorted_dst[ps * CAP + p0] = pd;
                        if (p1 < CAP) sorted_dst[s * CAP + p1] = dv;
                        ps = -1;
                    }
                }
            }
        }
        if (ps >= 0) {
            int p0 = atomicAdd(&deg[ps << 4], 1);
            if (p0 < CAP) sorted_dst[ps * CAP + p0] = pd;
        }
        return;
    }

    __shared__ float sh[4224];              // unioned buffer (16.9 KB)
    __shared__ int sflag;
    int tid = threadIdx.x;

    if (b == FILLB + L0B) {   // ---- layer-1 table producer, two phases ----
        // zero row post0[Nn]: OOB gather target for aggr
        if (tid < 16) {
            uint4 z; z.x = 0u; z.y = 0u; z.z = 0u; z.w = 0u;
            ((uint4*)(post0 + (size_t)Nn * 128))[tid] = z;
        }
        const int isbf = detect_bf16(B0, tid, &sflag);
        if (tid == 0) *flag_ws = sflag;
        // Phase A: B1 softmax -> smB1ws
        for (int i = tid; i < Cc * Mm * Gg; i += 256) sh[i] = ldin(B1, i, isbf);
        __syncthreads();
        if (tid < 128) sm_col(sh, (tid >> 3) * (Mm * Gg) + (tid & 7), Gg, Mm);
        __syncthreads();
        for (int i = tid; i < Cc * Mm * Gg; i += 256) smB1ws[i] = sh[i];
        __syncthreads();
        // Phase B: Q softmax -> smQgws ([g][i][l] relayout)
        for (int i = tid; i < Cc * Cc * Gg; i += 256) sh[i] = ldin(Q, i, isbf);
        __syncthreads();
        if (tid < 128) sm_col(sh, (tid >> 3) * Gg + (tid & 7), Cc * Gg, Cc);
        __syncthreads();
        for (int t = tid; t < Cc * Cc * Gg; t += 256) {
            int i = t >> 7, rem = t & 127, l = rem >> 3, g = rem & 7;
            smQgws[g * (Cc * Cc) + i * Cc + l] = sh[t];
        }
        return;
    }

    // ---- layer0 ----
    float* sB0sm = sh;                      // 4096, [c][m][g]
    float* sPism = sh + 4096;               // 128,  [c][g]
    const int isbf = detect_bf16(B0, tid, &sflag);

    for (int i = tid; i < Cc * Mm * Gg; i += 256) sB0sm[i] = ldin(B0, i, isbf);
    if (tid < Cc * Gg) sPism[tid] = ldin(Pi, tid, isbf);
    __syncthreads();
    if (tid < 128) {                        // B0 col (c,g): softmax over m, stride 8
        sm_col(sB0sm, (tid >> 3) * (Mm * Gg) + (tid & 7), Gg, Mm);
    } else if (tid < 128 + Gg) {            // Pi col g: softmax over c, stride 8
        sm_col(sPism, tid - 128, Gg, Cc);
    }
    __syncthreads();

    for (int idx = (b - FILLB) * 256 + tid; idx < Nn * Gg; idx += L0B * 256) {
        int n = idx >> 3, g = idx & 7;
        int xv = x[n];
        float u[Cc];
        float norm = 0.f;
#pragma unroll
        for (int c = 0; c < Cc; ++c) {
            float v = sPism[c * Gg + g] * sB0sm[c * (Mm * Gg) + xv * Gg + g];
            u[c] = v; norm += v;
        }
        float inv = 1.0f / norm;
        unsigned short h[Cc];
#pragma unroll
        for (int c = 0; c < Cc; ++c) h[c] = f2bf(u[c] * inv);
        uint4 w0, w1;
        w0.x = h[0] | (h[1] << 16);   w0.y = h[2] | (h[3] << 16);
        w0.z = h[4] | (h[5] << 16);   w0.w = h[6] | (h[7] << 16);
        w1.x = h[8] | (h[9] << 16);   w1.y = h[10] | (h[11] << 16);
        w1.z = h[12] | (h[13] << 16); w1.w = h[14] | (h[15] << 16);
        uint4* dst = (uint4*)(post0 + (size_t)n * 128 + g * 16);
        dst[0] = w0; dst[1] = w1;
        stout(out, (size_t)n * (2 * Gg) + g, logf(norm), isbf);
    }
}

// ---------------------------------------------------------------------------
// Kernel 2 (R12 rewrite): 2-deep cross-node pipeline.
//   iter(n): issue meta(n+2NW) | issue gather(n+NW)+B1(n+NW) | consume n.
//   Gather buffers double-buffered (2x 16 VGPR). OOB edges read zero row
//   post0[Nn] (no per-element cndmask). Q lives in bank-swizzled LDS
//   (addr = g*545 + i*34 + j -> bank = g+2i+j mod 32; dot reads are 2-way
//   = free). B1 values (2 scalars/node) prefetched from L2-resident global.
//   VGPR target <= 64 for 8 blocks/CU (launch_bounds(256,8)).
// ---------------------------------------------------------------------------
#define GL(vv, eb, sdreg, ddv) { int ej_ = (eb) + sub16; \
    int dn_ = __shfl(sdreg, ej_, 64); \
    dn_ = (ej_ < (ddv)) ? dn_ : Nn; \
    vv = *(const uint4*)(post0 + ((size_t)dn_ << 7) + moff); }
#define GACC(vv) { \
    acc[0] += bflo(vv.x); acc[1] += bfhi(vv.x); acc[2] += bflo(vv.y); acc[3] += bfhi(vv.y); \
    acc[4] += bflo(vv.z); acc[5] += bfhi(vv.z); acc[6] += bflo(vv.w); acc[7] += bfhi(vv.w); }

__global__ __launch_bounds__(256, 8) void aggr_layer1(
        const int* __restrict__ deg,        // padded stride 16
        const int* __restrict__ sorted_dst,
        const unsigned short* __restrict__ post0,
        const int* __restrict__ x,
        const float* __restrict__ smB1ws,
        const float* __restrict__ smQgws,
        const int* __restrict__ flag_ws,
        void* __restrict__ out) {
    __shared__ float sQ[4341];              // 17.4 KB swizzled Q table
    int tid = threadIdx.x;
    const int isbf = *flag_ws;
    for (int t = tid; t < Cc * Cc * Gg; t += 256) {
        int g = t >> 8, i = (t >> 4) & 15, j = t & 15;
        sQ[g * 545 + i * 34 + j] = smQgws[t];
    }
    __syncthreads();

    const int lane = tid & 63, wib = tid >> 6;
    const int sub16 = lane >> 4;            // which edge of the quad this lane reads
    const int moff  = (lane & 15) * 8;      // ushort offset within the 256B row
    const int ii = lane >> 3, gW = lane & 7;
    const int i0 = 2 * ii, i1 = i0 + 1;
    const float* qp = sQ + gW * 545 + i0 * 34;   // rows i0 (qp[0..15]) / i1 (qp[34..49])

    const int NW = NAB * 4;
    int n0 = blockIdx.x * 4 + wib;
    int n1 = n0 + NW, n2 = n0 + 2 * NW;

    // ---- prologue: meta(n0), meta(n1), gather(n0), B1(n0) ----
    int d0 = 0, sd0 = 0, x0v = 0;
    if (n0 < Nn) { d0 = deg[n0 * 16]; sd0 = sorted_dst[(size_t)n0 * CAP + lane]; x0v = x[n0]; }
    int d1 = 0, sd1 = 0, x1v = 0;
    if (n1 < Nn) { d1 = deg[n1 * 16]; sd1 = sorted_dst[(size_t)n1 * CAP + lane]; x1v = x[n1]; }
    uint4 bA0, bA1, bA2, bA3;
    bA0.x = bA0.y = bA0.z = bA0.w = 0u; bA1 = bA0; bA2 = bA0; bA3 = bA0;
    float b0c = 0.f, b1c = 0.f;
    if (n0 < Nn) {
        const int ddp = __builtin_amdgcn_readfirstlane(d0 < CAP ? d0 : CAP);
        GL(bA0, 0, sd0, ddp); GL(bA1, 4, sd0, ddp); GL(bA2, 8, sd0, ddp); GL(bA3, 12, sd0, ddp);
        b0c = smB1ws[i0 * (Mm * Gg) + x0v * Gg + gW];
        b1c = smB1ws[i1 * (Mm * Gg) + x0v * Gg + gW];
    }

    while (n0 < Nn) {
        // ---- stage 1: issue meta(n2) ----
        int d2 = 0, sd2 = 0, x2v = 0;
        if (n2 < Nn) { d2 = deg[n2 * 16]; sd2 = sorted_dst[(size_t)n2 * CAP + lane]; x2v = x[n2]; }

        // ---- stage 2: issue gather(n1) + B1(n1) ----
        uint4 bB0, bB1, bB2, bB3;
        bB0.x = bB0.y = bB0.z = bB0.w = 0u; bB1 = bB0; bB2 = bB0; bB3 = bB0;
        float b0n = 0.f, b1n = 0.f;
        if (n1 < Nn) {
            const int dd1 = __builtin_amdgcn_readfirstlane(d1 < CAP ? d1 : CAP);
            GL(bB0, 0, sd1, dd1); GL(bB1, 4, sd1, dd1); GL(bB2, 8, sd1, dd1); GL(bB3, 12, sd1, dd1);
            b0n = smB1ws[i0 * (Mm * Gg) + x1v * Gg + gW];
            b1n = smB1ws[i1 * (Mm * Gg) + x1v * Gg + gW];
        }

        // ---- stage 3: consume node n0 ----
        int nu0 = __builtin_amdgcn_readfirstlane(n0);
        const int dd0 = __builtin_amdgcn_readfirstlane(d0 < CAP ? d0 : CAP);
        float acc[8];
#pragma unroll
        for (int j = 0; j < 8; ++j) acc[j] = 0.f;
        GACC(bA0); GACC(bA1); GACC(bA2); GACC(bA3);
        for (int e = 16; e < dd0; e += 16) {        // deg>16 tail (~43% of nodes)
            uint4 t0, t1, t2, t3;
            GL(t0, e, sd0, dd0); GL(t1, e + 4, sd0, dd0);
            GL(t2, e + 8, sd0, dd0); GL(t3, e + 12, sd0, dd0);
            GACC(t0); GACC(t1); GACC(t2); GACC(t3);
        }

        // reduce the 4 edge sub-groups
#pragma unroll
        for (int j = 0; j < 8; ++j) {
            acc[j] += __shfl_xor(acc[j], 16, 64);
            acc[j] += __shfl_xor(acc[j], 32, 64);
        }
        // fused collect + dot (Q from swizzled LDS)
        float qa0 = 0.f, qa1 = 0.f;
#pragma unroll
        for (int j = 0; j < 8; ++j) {
            float t0 = __shfl(acc[j], 2 * gW, 64);       // aggr[gW][j]
            float t1 = __shfl(acc[j], 2 * gW + 1, 64);   // aggr[gW][8+j]
            qa0 += qp[j] * t0 + qp[8 + j] * t1;
            qa1 += qp[34 + j] * t0 + qp[42 + j] * t1;
        }
        float invd = 1.0f / fmaxf((float)d0, 1.0f);
        qa0 *= invd; qa1 *= invd;
        float v0 = b0c * qa0, v1 = b1c * qa1;
        float nrm = v0 + v1;
        nrm += __shfl_xor(nrm, 8, 64);
        nrm += __shfl_xor(nrm, 16, 64);
        nrm += __shfl_xor(nrm, 32, 64);
        float invn = 1.0f / nrm;
        size_t pbase = (size_t)Nn * 2 * Gg + (size_t)nu0 * (Cc * Gg);
        stout(out, pbase + i0 * Gg + gW, v0 * invn, isbf);
        stout(out, pbase + i1 * Gg + gW, v1 * invn, isbf);
        if (ii == 0) stout(out, (size_t)nu0 * (2 * Gg) + Gg + gW, logf(nrm), isbf);

        // ---- rotate pipeline ----
        n0 = n1; n1 = n2; n2 += NW;
        d0 = d1; sd0 = sd1; x0v = x1v;
        d1 = d2; sd1 = sd2; x1v = x2v;
        bA0 = bB0; bA1 = bB1; bA2 = bB2; bA3 = bB3;
        b0c = b0n; b1c = b1n;
    }
}

// ---------------------------------------------------------------------------
extern "C" void kernel_launch(void* const* d_in, const int* in_sizes, int n_in,
                              void* d_out, int out_size, void* d_ws, size_t ws_size,
                              hipStream_t stream) {
    const int* x  = (const int*)d_in[0];
    const int* ei = (const int*)d_in[1];
    const void* B0 = d_in[2];
    const void* Pi = d_in[3];
    const void* B1 = d_in[4];
    const void* Q  = d_in[5];

    // ws: flag(128) | smB1(4096) | smQg(2048) | post0 ((Nn+1) rows) | deg(pad) | sorted_dst
    float* ws = (float*)d_ws;
    int*   flag   = (int*)ws;                     // 1 (padded to 128)
    float* smB1ws = ws + 128;                     // 4096 [i][m][g]
    float* smQgws = smB1ws + 4096;                // 2048 [g][i][l]
    unsigned short* post0 = (unsigned short*)(smQgws + 2048);  // (Nn+1)*128 bf16 [n][g][c]
    int* deg        = (int*)(post0 + (size_t)(Nn + 1) * 128);  // Nn*16 (64B-padded counters)
    int* sorted_dst = deg + (size_t)Nn * 16;                   // Nn*CAP ints

    hipMemsetAsync(deg, 0, (size_t)Nn * 16 * sizeof(int), stream);

    fill_layer0<<<FILLB + L0B + 1, 256, 0, stream>>>(
        ei, x, B0, Pi, B1, Q, deg, sorted_dst, post0, smB1ws, smQgws, flag, d_out);

    aggr_layer1<<<NAB, 256, 0, stream>>>(
        deg, sorted_dst, post0, x, smB1ws, smQgws, flag, d_out);
}

// Round 4
// 154.832 us; speedup vs baseline: 2.0736x; 2.0736x over previous
//
#include <hip/hip_runtime.h>
#include <hip/hip_bf16.h>
#include <math.h>

#define Nn 50000
#define Ee 800000
#define Cc 16
#define Mm 32
#define Gg 8
#define CAP 64            // per-node edge-slot capacity (max deg ~35 for this input)

#define FILLB 1536        // fill blocks (192 per XCD group)
#define L0B 400           // layer0 blocks (grid-strided)
#define NAB 2048          // aggr blocks (4 waves each)
#define NPG (Nn / 8)      // 6250 src nodes per XCD group

// ---------------------------------------------------------------------------
// helpers
// ---------------------------------------------------------------------------
__device__ __forceinline__ float ldin(const void* p, int idx, int isbf) {
    if (isbf) return __bfloat162float(((const __hip_bfloat16*)p)[idx]);
    return ((const float*)p)[idx];
}
__device__ __forceinline__ void stout(void* p, size_t idx, float v, int isbf) {
    if (isbf) ((__hip_bfloat16*)p)[idx] = __float2bfloat16(v);
    else ((float*)p)[idx] = v;
}
__device__ __forceinline__ unsigned short f2bf(float f) {    // RNE f32 -> bf16 bits
    unsigned u = __float_as_uint(f);
    return (unsigned short)((u + 0x7FFFu + ((u >> 16) & 1u)) >> 16);
}
__device__ __forceinline__ float bflo(unsigned v) { return __uint_as_float(v << 16); }
__device__ __forceinline__ float bfhi(unsigned v) { return __uint_as_float(v & 0xffff0000u); }

__device__ __forceinline__ int detect_bf16(const void* B0, int tid, int* sflag) {
    if (tid < 64) {
        unsigned wv = ((const unsigned*)B0)[tid];
        unsigned ex = (wv >> 7) & 0xFFu;
        unsigned long long m = __ballot(ex >= 120u && ex <= 130u);
        if (tid == 0) *sflag = (__popcll(m) >= 48) ? 1 : 0;
    }
    __syncthreads();
    return *sflag;
}

// in-place softmax of one LDS column: entries base + k*stride, k in [0,cnt)
__device__ __forceinline__ void sm_col(float* a, int base, int stride, int cnt) {
    float mx = -1e30f;
    for (int k = 0; k < cnt; ++k) mx = fmaxf(mx, a[base + k * stride]);
    float s = 0.f;
    for (int k = 0; k < cnt; ++k) {
        float e = __expf(a[base + k * stride] - mx);
        a[base + k * stride] = e;
        s += e;
    }
    float inv = 1.0f / s;
    for (int k = 0; k < cnt; ++k) a[base + k * stride] *= inv;
}

// ---------------------------------------------------------------------------
// Kernel 1: blocks [0,FILLB)           = bucketed fill+count
//           blocks [FILLB,FILLB+L0B)   = layer0 (self-staged B0/Pi in sh[])
//           block  FILLB+L0B           = layer-1 table producer + zero-row
// deg padded to one counter per 64B line (stride 16 ints).
// ---------------------------------------------------------------------------
__global__ void fill_layer0(const int* __restrict__ ei,
                            const int* __restrict__ x,
                            const void* __restrict__ B0,
                            const void* __restrict__ Pi,
                            const void* __restrict__ B1,
                            const void* __restrict__ Q,
                            int* __restrict__ deg,          // padded: deg[n*16]
                            int* __restrict__ sorted_dst,
                            unsigned short* __restrict__ post0,
                            float* __restrict__ smB1ws,     // [i][m][g] fp32
                            float* __restrict__ smQgws,     // [g][i][l] fp32
                            int* __restrict__ flag_ws,
                            void* __restrict__ out) {
    int b = blockIdx.x;
    if (b < FILLB) {   // ---- fill: group owns contiguous node range (XCD-local) ----
        int grp = b & 7, sub = b >> 3;
        int lo = grp * NPG, hi = lo + NPG;
        const int NQ = Ee / 4;                      // 200000 int4 quads of src
        const int stride = (FILLB >> 3) * 256;      // 49152 threads per group
        const int4* ei4 = (const int4*)ei;
        int ps = -1, pd = 0;                        // pending (src,dst) pair
        for (int q = sub * 256 + threadIdx.x; q < NQ; q += stride) {
            int4 sv = ei4[q];
#pragma unroll
            for (int k = 0; k < 4; ++k) {
                int s = (k == 0) ? sv.x : (k == 1) ? sv.y : (k == 2) ? sv.z : sv.w;
                if (s >= lo && s < hi) {
                    int dv = ei[Ee + 4 * q + k];
                    if (ps < 0) { ps = s; pd = dv; }
                    else {
                        int p0 = atomicAdd(&deg[ps << 4], 1);   // padded counters
                        int p1 = atomicAdd(&deg[s << 4], 1);
                        if (p0 < CAP) sorted_dst[ps * CAP + p0] = pd;
                        if (p1 < CAP) sorted_dst[s * CAP + p1] = dv;
                        ps = -1;
                    }
                }
            }
        }
        if (ps >= 0) {
            int p0 = atomicAdd(&deg[ps << 4], 1);
            if (p0 < CAP) sorted_dst[ps * CAP + p0] = pd;
        }
        return;
    }

    __shared__ float sh[4224];              // unioned buffer (16.9 KB)
    __shared__ int sflag;
    int tid = threadIdx.x;

    if (b == FILLB + L0B) {   // ---- layer-1 table producer, two phases ----
        // zero row post0[Nn]: OOB gather target for aggr
        if (tid < 16) {
            uint4 z; z.x = 0u; z.y = 0u; z.z = 0u; z.w = 0u;
            ((uint4*)(post0 + (size_t)Nn * 128))[tid] = z;
        }
        const int isbf = detect_bf16(B0, tid, &sflag);
        if (tid == 0) *flag_ws = sflag;
        // Phase A: B1 softmax -> smB1ws
        for (int i = tid; i < Cc * Mm * Gg; i += 256) sh[i] = ldin(B1, i, isbf);
        __syncthreads();
        if (tid < 128) sm_col(sh, (tid >> 3) * (Mm * Gg) + (tid & 7), Gg, Mm);
        __syncthreads();
        for (int i = tid; i < Cc * Mm * Gg; i += 256) smB1ws[i] = sh[i];
        __syncthreads();
        // Phase B: Q softmax -> smQgws ([g][i][l] relayout)
        for (int i = tid; i < Cc * Cc * Gg; i += 256) sh[i] = ldin(Q, i, isbf);
        __syncthreads();
        if (tid < 128) sm_col(sh, (tid >> 3) * Gg + (tid & 7), Cc * Gg, Cc);
        __syncthreads();
        for (int t = tid; t < Cc * Cc * Gg; t += 256) {
            int i = t >> 7, rem = t & 127, l = rem >> 3, g = rem & 7;
            smQgws[g * (Cc * Cc) + i * Cc + l] = sh[t];
        }
        return;
    }

    // ---- layer0 ----
    float* sB0sm = sh;                      // 4096, [c][m][g]
    float* sPism = sh + 4096;               // 128,  [c][g]
    const int isbf = detect_bf16(B0, tid, &sflag);

    for (int i = tid; i < Cc * Mm * Gg; i += 256) sB0sm[i] = ldin(B0, i, isbf);
    if (tid < Cc * Gg) sPism[tid] = ldin(Pi, tid, isbf);
    __syncthreads();
    if (tid < 128) {                        // B0 col (c,g): softmax over m, stride 8
        sm_col(sB0sm, (tid >> 3) * (Mm * Gg) + (tid & 7), Gg, Mm);
    } else if (tid < 128 + Gg) {            // Pi col g: softmax over c, stride 8
        sm_col(sPism, tid - 128, Gg, Cc);
    }
    __syncthreads();

    for (int idx = (b - FILLB) * 256 + tid; idx < Nn * Gg; idx += L0B * 256) {
        int n = idx >> 3, g = idx & 7;
        int xv = x[n];
        float u[Cc];
        float norm = 0.f;
#pragma unroll
        for (int c = 0; c < Cc; ++c) {
            float v = sPism[c * Gg + g] * sB0sm[c * (Mm * Gg) + xv * Gg + g];
            u[c] = v; norm += v;
        }
        float inv = 1.0f / norm;
        unsigned short h[Cc];
#pragma unroll
        for (int c = 0; c < Cc; ++c) h[c] = f2bf(u[c] * inv);
        uint4 w0, w1;
        w0.x = h[0] | (h[1] << 16);   w0.y = h[2] | (h[3] << 16);
        w0.z = h[4] | (h[5] << 16);   w0.w = h[6] | (h[7] << 16);
        w1.x = h[8] | (h[9] << 16);   w1.y = h[10] | (h[11] << 16);
        w1.z = h[12] | (h[13] << 16); w1.w = h[14] | (h[15] << 16);
        uint4* dst = (uint4*)(post0 + (size_t)n * 128 + g * 16);
        dst[0] = w0; dst[1] = w1;
        stout(out, (size_t)n * (2 * Gg) + g, logf(norm), isbf);
    }
}

// ---------------------------------------------------------------------------
// Kernel 2 (R13 resubmit): depth-2 cross-node pipeline, register-budgeted.
//   - NO forced launch_bounds min-occupancy (R12's cap caused 850MB of
//     scratch spill traffic; validity check this round = WRITE_SIZE ~26MB).
//   - 32-bit gather addressing: off = (dn<<8)+mbyte vs uniform post0 base
//     -> global_load_dwordx4 v, voff, s[base]: 1 addr VGPR, not a 64b pair.
//   - metadata via readfirstlane'd node index -> s_load (scalar path).
//   - Q in bank-swizzled LDS (17.4KB, 2-way reads = free); B1 pair per node
//     prefetched from L2-resident smB1ws; OOB edges read zero row post0[Nn].
// ---------------------------------------------------------------------------
#define GL(vv, eb, sdreg, ddv) { int ej_ = (eb) + sub16; \
    int dn_ = __shfl(sdreg, ej_, 64); \
    dn_ = (ej_ < (ddv)) ? dn_ : Nn; \
    unsigned off_ = ((unsigned)dn_ << 8) + mbyte; \
    vv = *(const uint4*)((const char*)post0 + off_); }
#define GACC(vv) { \
    acc[0] += bflo(vv.x); acc[1] += bfhi(vv.x); acc[2] += bflo(vv.y); acc[3] += bfhi(vv.y); \
    acc[4] += bflo(vv.z); acc[5] += bfhi(vv.z); acc[6] += bflo(vv.w); acc[7] += bfhi(vv.w); }

__global__ __launch_bounds__(256) void aggr_layer1(
        const int* __restrict__ deg,        // padded stride 16
        const int* __restrict__ sorted_dst,
        const unsigned short* __restrict__ post0,
        const int* __restrict__ x,
        const float* __restrict__ smB1ws,
        const float* __restrict__ smQgws,
        const int* __restrict__ flag_ws,
        void* __restrict__ out) {
    __shared__ float sQ[4341];              // 17.4 KB swizzled Q table
    int tid = threadIdx.x;
    const int isbf = *flag_ws;
    for (int t = tid; t < Cc * Cc * Gg; t += 256) {
        int g = t >> 8, i = (t >> 4) & 15, j = t & 15;
        sQ[g * 545 + i * 34 + j] = smQgws[t];
    }
    __syncthreads();

    const int lane = tid & 63, wib = tid >> 6;
    const int sub16 = lane >> 4;            // which edge of the quad this lane reads
    const unsigned mbyte = (unsigned)((lane & 15) * 16);   // byte offset in 256B row
    const int ii = lane >> 3, gW = lane & 7;
    const int i0 = 2 * ii, i1 = i0 + 1;
    const float* qp = sQ + gW * 545 + i0 * 34;   // rows i0 (qp[0..15]) / i1 (qp[34..49])

    const int NW = NAB * 4;
    int n0 = blockIdx.x * 4 + wib;

    // ---- prologue: meta(n0), meta(n1), gather(n0), B1(n0) ----
    int d0 = 0, sd0 = 0, x0v = 0;
    if (n0 < Nn) {
        int nu = __builtin_amdgcn_readfirstlane(n0);
        d0 = deg[nu << 4]; sd0 = sorted_dst[nu * CAP + lane]; x0v = x[nu];
    }
    int d1 = 0, sd1 = 0, x1v = 0;
    if (n0 + NW < Nn) {
        int nu = __builtin_amdgcn_readfirstlane(n0 + NW);
        d1 = deg[nu << 4]; sd1 = sorted_dst[nu * CAP + lane]; x1v = x[nu];
    }
    uint4 bA0, bA1, bA2, bA3;
    bA0.x = bA0.y = bA0.z = bA0.w = 0u; bA1 = bA0; bA2 = bA0; bA3 = bA0;
    float b0c = 0.f, b1c = 0.f;
    if (n0 < Nn) {
        const int ddp = d0 < CAP ? d0 : CAP;
        GL(bA0, 0, sd0, ddp); GL(bA1, 4, sd0, ddp); GL(bA2, 8, sd0, ddp); GL(bA3, 12, sd0, ddp);
        b0c = smB1ws[i0 * (Mm * Gg) + x0v * Gg + gW];
        b1c = smB1ws[i1 * (Mm * Gg) + x0v * Gg + gW];
    }

    while (n0 < Nn) {
        // ---- stage 1: issue meta(n0+2NW) via scalar path ----
        int d2 = 0, sd2 = 0, x2v = 0;
        if (n0 + 2 * NW < Nn) {
            int nu = __builtin_amdgcn_readfirstlane(n0 + 2 * NW);
            d2 = deg[nu << 4]; sd2 = sorted_dst[nu * CAP + lane]; x2v = x[nu];
        }

        // ---- stage 2: issue gather(n0+NW) + B1(n0+NW) ----
        uint4 bB0, bB1, bB2, bB3;
        bB0.x = bB0.y = bB0.z = bB0.w = 0u; bB1 = bB0; bB2 = bB0; bB3 = bB0;
        float b0n = 0.f, b1n = 0.f;
        if (n0 + NW < Nn) {
            const int dd1 = d1 < CAP ? d1 : CAP;
            GL(bB0, 0, sd1, dd1); GL(bB1, 4, sd1, dd1); GL(bB2, 8, sd1, dd1); GL(bB3, 12, sd1, dd1);
            b0n = smB1ws[i0 * (Mm * Gg) + x1v * Gg + gW];
            b1n = smB1ws[i1 * (Mm * Gg) + x1v * Gg + gW];
        }

        // ---- stage 3: consume node n0 ----
        int nu0 = __builtin_amdgcn_readfirstlane(n0);
        const int dd0 = d0 < CAP ? d0 : CAP;
        float acc[8];
#pragma unroll
        for (int j = 0; j < 8; ++j) acc[j] = 0.f;
        GACC(bA0); GACC(bA1); GACC(bA2); GACC(bA3);
        for (int e = 16; e < dd0; e += 16) {        // deg>16 tail (~43% of nodes)
            uint4 t0, t1, t2, t3;
            GL(t0, e, sd0, dd0); GL(t1, e + 4, sd0, dd0);
            GL(t2, e + 8, sd0, dd0); GL(t3, e + 12, sd0, dd0);
            GACC(t0); GACC(t1); GACC(t2); GACC(t3);
        }

        // reduce the 4 edge sub-groups
#pragma unroll
        for (int j = 0; j < 8; ++j) {
            acc[j] += __shfl_xor(acc[j], 16, 64);
            acc[j] += __shfl_xor(acc[j], 32, 64);
        }
        // fused collect + dot (Q from swizzled LDS)
        float qa0 = 0.f, qa1 = 0.f;
#pragma unroll
        for (int j = 0; j < 8; ++j) {
            float t0 = __shfl(acc[j], 2 * gW, 64);       // aggr[gW][j]
            float t1 = __shfl(acc[j], 2 * gW + 1, 64);   // aggr[gW][8+j]
            qa0 += qp[j] * t0 + qp[8 + j] * t1;
            qa1 += qp[34 + j] * t0 + qp[42 + j] * t1;
        }
        float invd = 1.0f / fmaxf((float)d0, 1.0f);
        qa0 *= invd; qa1 *= invd;
        float v0 = b0c * qa0, v1 = b1c * qa1;
        float nrm = v0 + v1;
        nrm += __shfl_xor(nrm, 8, 64);
        nrm += __shfl_xor(nrm, 16, 64);
        nrm += __shfl_xor(nrm, 32, 64);
        float invn = 1.0f / nrm;
        size_t pbase = (size_t)Nn * 2 * Gg + (size_t)nu0 * (Cc * Gg);
        stout(out, pbase + i0 * Gg + gW, v0 * invn, isbf);
        stout(out, pbase + i1 * Gg + gW, v1 * invn, isbf);
        if (ii == 0) stout(out, (size_t)nu0 * (2 * Gg) + Gg + gW, logf(nrm), isbf);

        // ---- rotate pipeline ----
        n0 += NW;
        d0 = d1; sd0 = sd1; x0v = x1v;
        d1 = d2; sd1 = sd2; x1v = x2v;
        bA0 = bB0; bA1 = bB1; bA2 = bB2; bA3 = bB3;
        b0c = b0n; b1c = b1n;
    }
}

// ---------------------------------------------------------------------------
extern "C" void kernel_launch(void* const* d_in, const int* in_sizes, int n_in,
                              void* d_out, int out_size, void* d_ws, size_t ws_size,
                              hipStream_t stream) {
    const int* x  = (const int*)d_in[0];
    const int* ei = (const int*)d_in[1];
    const void* B0 = d_in[2];
    const void* Pi = d_in[3];
    const void* B1 = d_in[4];
    const void* Q  = d_in[5];

    // ws: flag(128) | smB1(4096) | smQg(2048) | post0 ((Nn+1) rows) | deg(pad) | sorted_dst
    float* ws = (float*)d_ws;
    int*   flag   = (int*)ws;                     // 1 (padded to 128)
    float* smB1ws = ws + 128;                     // 4096 [i][m][g]
    float* smQgws = smB1ws + 4096;                // 2048 [g][i][l]
    unsigned short* post0 = (unsigned short*)(smQgws + 2048);  // (Nn+1)*128 bf16 [n][g][c]
    int* deg        = (int*)(post0 + (size_t)(Nn + 1) * 128);  // Nn*16 (64B-padded counters)
    int* sorted_dst = deg + (size_t)Nn * 16;                   // Nn*CAP ints

    hipMemsetAsync(deg, 0, (size_t)Nn * 16 * sizeof(int), stream);

    fill_layer0<<<FILLB + L0B + 1, 256, 0, stream>>>(
        ei, x, B0, Pi, B1, Q, deg, sorted_dst, post0, smB1ws, smQgws, flag, d_out);

    aggr_layer1<<<NAB, 256, 0, stream>>>(
        deg, sorted_dst, post0, x, smB1ws, smQgws, flag, d_out);
}

// Round 5
// 141.044 us; speedup vs baseline: 2.2763x; 1.0978x over previous
//
#include <hip/hip_runtime.h>
#include <hip/hip_bf16.h>
#include <math.h>

#define Nn 50000
#define Ee 800000
#define Cc 16
#define Mm 32
#define Gg 8
#define CAP 64            // per-node edge-slot capacity (max deg ~35 for this input)

#define P1B 256           // pass-1 bucket-scatter blocks (3125 edges each)
#define NBK 128           // src-range buckets
#define BSZ 392           // nodes per bucket (128*392 = 50176 >= 50000)
#define SEGCAP 64         // per (bucket, block) segment capacity (mean 24.5, P(ovfl)~1e-9)
#define L0B 400           // layer0 blocks (grid-strided)
#define NAB 2048          // aggr blocks (4 waves each)

// ---------------------------------------------------------------------------
// helpers
// ---------------------------------------------------------------------------
__device__ __forceinline__ float ldin(const void* p, int idx, int isbf) {
    if (isbf) return __bfloat162float(((const __hip_bfloat16*)p)[idx]);
    return ((const float*)p)[idx];
}
__device__ __forceinline__ void stout(void* p, size_t idx, float v, int isbf) {
    if (isbf) ((__hip_bfloat16*)p)[idx] = __float2bfloat16(v);
    else ((float*)p)[idx] = v;
}
__device__ __forceinline__ unsigned short f2bf(float f) {    // RNE f32 -> bf16 bits
    unsigned u = __float_as_uint(f);
    return (unsigned short)((u + 0x7FFFu + ((u >> 16) & 1u)) >> 16);
}
__device__ __forceinline__ float bflo(unsigned v) { return __uint_as_float(v << 16); }
__device__ __forceinline__ float bfhi(unsigned v) { return __uint_as_float(v & 0xffff0000u); }

__device__ __forceinline__ int detect_bf16(const void* B0, int tid, int* sflag) {
    if (tid < 64) {
        unsigned wv = ((const unsigned*)B0)[tid];
        unsigned ex = (wv >> 7) & 0xFFu;
        unsigned long long m = __ballot(ex >= 120u && ex <= 130u);
        if (tid == 0) *sflag = (__popcll(m) >= 48) ? 1 : 0;
    }
    __syncthreads();
    return *sflag;
}

// in-place softmax of one LDS column: entries base + k*stride, k in [0,cnt)
__device__ __forceinline__ void sm_col(float* a, int base, int stride, int cnt) {
    float mx = -1e30f;
    for (int k = 0; k < cnt; ++k) mx = fmaxf(mx, a[base + k * stride]);
    float s = 0.f;
    for (int k = 0; k < cnt; ++k) {
        float e = __expf(a[base + k * stride] - mx);
        a[base + k * stride] = e;
        s += e;
    }
    float inv = 1.0f / s;
    for (int k = 0; k < cnt; ++k) a[base + k * stride] *= inv;
}

// ---------------------------------------------------------------------------
// Kernel 1: blocks [0,P1B)          = pass-1 edge bucket-scatter (LDS atomics only)
//           blocks [P1B,P1B+L0B)    = layer0 (self-staged B0/Pi)
//           block  P1B+L0B          = layer-1 table producer + zero-row
// R14: global atomicAdd ELIMINATED (R2/R4 evidence: chip-wide atomic service
// throughput ~18 ops/ns was the ~45us wall, independent of address padding).
// Pass-1 routes each edge into one of 128 src-range buckets via LDS atomics,
// packing (s_local<<16)|d into u32 segments of SEGCAP per (bucket, block).
// ---------------------------------------------------------------------------
__global__ void bucket_layer0(const int* __restrict__ ei,
                              const int* __restrict__ x,
                              const void* __restrict__ B0,
                              const void* __restrict__ Pi,
                              const void* __restrict__ B1,
                              const void* __restrict__ Q,
                              unsigned* __restrict__ segbuf,   // [NBK][P1B][SEGCAP]
                              int* __restrict__ segcnt,        // [NBK][P1B]
                              unsigned short* __restrict__ post0,
                              float* __restrict__ smB1ws,      // [i][m][g] fp32
                              float* __restrict__ smQgws,      // [g][i][l] fp32
                              int* __restrict__ flag_ws,
                              void* __restrict__ out) {
    int b = blockIdx.x, tid = threadIdx.x;
    __shared__ unsigned shb[128 + NBK * SEGCAP];   // 33.3 KB unioned buffer
    __shared__ int sflag;

    if (b < P1B) {   // ---- pass 1: bucket scatter ----
        int* scnt = (int*)shb;           // 128 counters
        unsigned* sstage = shb + 128;    // 128*64 staged packed edges
        for (int i = tid; i < NBK; i += 256) scnt[i] = 0;
        __syncthreads();
        const int base = b * (Ee / P1B);         // 3125 edges per block, exact
        const int end  = base + (Ee / P1B);
        for (int e = base + tid; e < end; e += 256) {
            int s = ei[e];
            int d = ei[Ee + e];
            int bk = s / BSZ;                    // magic-mul division
            int pos = atomicAdd(&scnt[bk], 1);   // LDS atomic (on-CU, cheap)
            if (pos < SEGCAP)
                sstage[bk * SEGCAP + pos] = ((unsigned)(s - bk * BSZ) << 16) | (unsigned)d;
        }
        __syncthreads();
        for (int idx = tid; idx < NBK * SEGCAP; idx += 256) {   // coalesced flush
            int bk = idx >> 6;
            int i  = idx & (SEGCAP - 1);
            int c  = scnt[bk]; c = c < SEGCAP ? c : SEGCAP;
            if (i < c)
                segbuf[((size_t)bk * P1B + b) * SEGCAP + i] = sstage[idx];
        }
        for (int i = tid; i < NBK; i += 256) {
            int c = scnt[i]; c = c < SEGCAP ? c : SEGCAP;
            segcnt[i * P1B + b] = c;
        }
        return;
    }

    float* sh = (float*)shb;                // alias: 4224 floats used

    if (b == P1B + L0B) {   // ---- layer-1 table producer, two phases ----
        // zero row post0[Nn]: OOB gather target for aggr
        if (tid < 16) {
            uint4 z; z.x = 0u; z.y = 0u; z.z = 0u; z.w = 0u;
            ((uint4*)(post0 + (size_t)Nn * 128))[tid] = z;
        }
        const int isbf = detect_bf16(B0, tid, &sflag);
        if (tid == 0) *flag_ws = sflag;
        // Phase A: B1 softmax -> smB1ws
        for (int i = tid; i < Cc * Mm * Gg; i += 256) sh[i] = ldin(B1, i, isbf);
        __syncthreads();
        if (tid < 128) sm_col(sh, (tid >> 3) * (Mm * Gg) + (tid & 7), Gg, Mm);
        __syncthreads();
        for (int i = tid; i < Cc * Mm * Gg; i += 256) smB1ws[i] = sh[i];
        __syncthreads();
        // Phase B: Q softmax -> smQgws ([g][i][l] relayout)
        for (int i = tid; i < Cc * Cc * Gg; i += 256) sh[i] = ldin(Q, i, isbf);
        __syncthreads();
        if (tid < 128) sm_col(sh, (tid >> 3) * Gg + (tid & 7), Cc * Gg, Cc);
        __syncthreads();
        for (int t = tid; t < Cc * Cc * Gg; t += 256) {
            int i = t >> 7, rem = t & 127, l = rem >> 3, g = rem & 7;
            smQgws[g * (Cc * Cc) + i * Cc + l] = sh[t];
        }
        return;
    }

    // ---- layer0 ----
    float* sB0sm = sh;                      // 4096, [c][m][g]
    float* sPism = sh + 4096;               // 128,  [c][g]
    const int isbf = detect_bf16(B0, tid, &sflag);

    for (int i = tid; i < Cc * Mm * Gg; i += 256) sB0sm[i] = ldin(B0, i, isbf);
    if (tid < Cc * Gg) sPism[tid] = ldin(Pi, tid, isbf);
    __syncthreads();
    if (tid < 128) {                        // B0 col (c,g): softmax over m, stride 8
        sm_col(sB0sm, (tid >> 3) * (Mm * Gg) + (tid & 7), Gg, Mm);
    } else if (tid < 128 + Gg) {            // Pi col g: softmax over c, stride 8
        sm_col(sPism, tid - 128, Gg, Cc);
    }
    __syncthreads();

    for (int idx = (b - P1B) * 256 + tid; idx < Nn * Gg; idx += L0B * 256) {
        int n = idx >> 3, g = idx & 7;
        int xv = x[n];
        float u[Cc];
        float norm = 0.f;
#pragma unroll
        for (int c = 0; c < Cc; ++c) {
            float v = sPism[c * Gg + g] * sB0sm[c * (Mm * Gg) + xv * Gg + g];
            u[c] = v; norm += v;
        }
        float inv = 1.0f / norm;
        unsigned short h[Cc];
#pragma unroll
        for (int c = 0; c < Cc; ++c) h[c] = f2bf(u[c] * inv);
        uint4 w0, w1;
        w0.x = h[0] | (h[1] << 16);   w0.y = h[2] | (h[3] << 16);
        w0.z = h[4] | (h[5] << 16);   w0.w = h[6] | (h[7] << 16);
        w1.x = h[8] | (h[9] << 16);   w1.y = h[10] | (h[11] << 16);
        w1.z = h[12] | (h[13] << 16); w1.w = h[14] | (h[15] << 16);
        uint4* dst = (uint4*)(post0 + (size_t)n * 128 + g * 16);
        dst[0] = w0; dst[1] = w1;
        stout(out, (size_t)n * (2 * Gg) + g, logf(norm), isbf);
    }
}

// ---------------------------------------------------------------------------
// Kernel 2 (new): placement. Block = bucket (392 nodes, LDS counters).
// Thread j drains pass-1 segment (bucket b, block j): LDS atomicAdd gives the
// slot, scattered store into sorted_dst, final deg written from LDS.
// No global atomics anywhere; no deg memset needed.
// ---------------------------------------------------------------------------
__global__ __launch_bounds__(256) void place_edges(
        const unsigned* __restrict__ segbuf,
        const int* __restrict__ segcnt,
        int* __restrict__ deg,
        int* __restrict__ sorted_dst) {
    __shared__ int cnt[BSZ];
    int b = blockIdx.x, tid = threadIdx.x;
    for (int i = tid; i < BSZ; i += 256) cnt[i] = 0;
    __syncthreads();
    int c = segcnt[b * P1B + tid];                       // 256 threads == P1B segments
    const unsigned* sp = segbuf + ((size_t)b * P1B + tid) * SEGCAP;
    int nbase = b * BSZ;
    unsigned pk = (c > 0) ? sp[0] : 0u;                  // 1-deep prefetch
    for (int i = 0; i < c; ++i) {
        unsigned nx = (i + 1 < c) ? sp[i + 1] : 0u;
        int sl = (int)(pk >> 16);
        int d  = (int)(pk & 0xffffu);
        int pos = atomicAdd(&cnt[sl], 1);                // LDS atomic
        if (pos < CAP) sorted_dst[(nbase + sl) * CAP + pos] = d;
        pk = nx;
    }
    __syncthreads();
    for (int i = tid; i < BSZ; i += 256) {
        int n = nbase + i;
        if (n < Nn) deg[n] = cnt[i];
    }
}

// ---------------------------------------------------------------------------
// Kernel 3: fused aggregation + layer1 — IDENTICAL to R13 except deg is now
// un-padded (deg[nu], was deg[nu<<4]).
// ---------------------------------------------------------------------------
#define GL(vv, eb, sdreg, ddv) { int ej_ = (eb) + sub16; \
    int dn_ = __shfl(sdreg, ej_, 64); \
    dn_ = (ej_ < (ddv)) ? dn_ : Nn; \
    unsigned off_ = ((unsigned)dn_ << 8) + mbyte; \
    vv = *(const uint4*)((const char*)post0 + off_); }
#define GACC(vv) { \
    acc[0] += bflo(vv.x); acc[1] += bfhi(vv.x); acc[2] += bflo(vv.y); acc[3] += bfhi(vv.y); \
    acc[4] += bflo(vv.z); acc[5] += bfhi(vv.z); acc[6] += bflo(vv.w); acc[7] += bfhi(vv.w); }

__global__ __launch_bounds__(256) void aggr_layer1(
        const int* __restrict__ deg,
        const int* __restrict__ sorted_dst,
        const unsigned short* __restrict__ post0,
        const int* __restrict__ x,
        const float* __restrict__ smB1ws,
        const float* __restrict__ smQgws,
        const int* __restrict__ flag_ws,
        void* __restrict__ out) {
    __shared__ float sQ[4341];              // 17.4 KB swizzled Q table
    int tid = threadIdx.x;
    const int isbf = *flag_ws;
    for (int t = tid; t < Cc * Cc * Gg; t += 256) {
        int g = t >> 8, i = (t >> 4) & 15, j = t & 15;
        sQ[g * 545 + i * 34 + j] = smQgws[t];
    }
    __syncthreads();

    const int lane = tid & 63, wib = tid >> 6;
    const int sub16 = lane >> 4;            // which edge of the quad this lane reads
    const unsigned mbyte = (unsigned)((lane & 15) * 16);   // byte offset in 256B row
    const int ii = lane >> 3, gW = lane & 7;
    const int i0 = 2 * ii, i1 = i0 + 1;
    const float* qp = sQ + gW * 545 + i0 * 34;   // rows i0 (qp[0..15]) / i1 (qp[34..49])

    const int NW = NAB * 4;
    int n0 = blockIdx.x * 4 + wib;

    // ---- prologue: meta(n0), meta(n1), gather(n0), B1(n0) ----
    int d0 = 0, sd0 = 0, x0v = 0;
    if (n0 < Nn) {
        int nu = __builtin_amdgcn_readfirstlane(n0);
        d0 = deg[nu]; sd0 = sorted_dst[nu * CAP + lane]; x0v = x[nu];
    }
    int d1 = 0, sd1 = 0, x1v = 0;
    if (n0 + NW < Nn) {
        int nu = __builtin_amdgcn_readfirstlane(n0 + NW);
        d1 = deg[nu]; sd1 = sorted_dst[nu * CAP + lane]; x1v = x[nu];
    }
    uint4 bA0, bA1, bA2, bA3;
    bA0.x = bA0.y = bA0.z = bA0.w = 0u; bA1 = bA0; bA2 = bA0; bA3 = bA0;
    float b0c = 0.f, b1c = 0.f;
    if (n0 < Nn) {
        const int ddp = d0 < CAP ? d0 : CAP;
        GL(bA0, 0, sd0, ddp); GL(bA1, 4, sd0, ddp); GL(bA2, 8, sd0, ddp); GL(bA3, 12, sd0, ddp);
        b0c = smB1ws[i0 * (Mm * Gg) + x0v * Gg + gW];
        b1c = smB1ws[i1 * (Mm * Gg) + x0v * Gg + gW];
    }

    while (n0 < Nn) {
        // ---- stage 1: issue meta(n0+2NW) via scalar path ----
        int d2 = 0, sd2 = 0, x2v = 0;
        if (n0 + 2 * NW < Nn) {
            int nu = __builtin_amdgcn_readfirstlane(n0 + 2 * NW);
            d2 = deg[nu]; sd2 = sorted_dst[nu * CAP + lane]; x2v = x[nu];
        }

        // ---- stage 2: issue gather(n0+NW) + B1(n0+NW) ----
        uint4 bB0, bB1, bB2, bB3;
        bB0.x = bB0.y = bB0.z = bB0.w = 0u; bB1 = bB0; bB2 = bB0; bB3 = bB0;
        float b0n = 0.f, b1n = 0.f;
        if (n0 + NW < Nn) {
            const int dd1 = d1 < CAP ? d1 : CAP;
            GL(bB0, 0, sd1, dd1); GL(bB1, 4, sd1, dd1); GL(bB2, 8, sd1, dd1); GL(bB3, 12, sd1, dd1);
            b0n = smB1ws[i0 * (Mm * Gg) + x1v * Gg + gW];
            b1n = smB1ws[i1 * (Mm * Gg) + x1v * Gg + gW];
        }

        // ---- stage 3: consume node n0 ----
        int nu0 = __builtin_amdgcn_readfirstlane(n0);
        const int dd0 = d0 < CAP ? d0 : CAP;
        float acc[8];
#pragma unroll
        for (int j = 0; j < 8; ++j) acc[j] = 0.f;
        GACC(bA0); GACC(bA1); GACC(bA2); GACC(bA3);
        for (int e = 16; e < dd0; e += 16) {        // deg>16 tail (~43% of nodes)
            uint4 t0, t1, t2, t3;
            GL(t0, e, sd0, dd0); GL(t1, e + 4, sd0, dd0);
            GL(t2, e + 8, sd0, dd0); GL(t3, e + 12, sd0, dd0);
            GACC(t0); GACC(t1); GACC(t2); GACC(t3);
        }

        // reduce the 4 edge sub-groups
#pragma unroll
        for (int j = 0; j < 8; ++j) {
            acc[j] += __shfl_xor(acc[j], 16, 64);
            acc[j] += __shfl_xor(acc[j], 32, 64);
        }
        // fused collect + dot (Q from swizzled LDS)
        float qa0 = 0.f, qa1 = 0.f;
#pragma unroll
        for (int j = 0; j < 8; ++j) {
            float t0 = __shfl(acc[j], 2 * gW, 64);       // aggr[gW][j]
            float t1 = __shfl(acc[j], 2 * gW + 1, 64);   // aggr[gW][8+j]
            qa0 += qp[j] * t0 + qp[8 + j] * t1;
            qa1 += qp[34 + j] * t0 + qp[42 + j] * t1;
        }
        float invd = 1.0f / fmaxf((float)d0, 1.0f);
        qa0 *= invd; qa1 *= invd;
        float v0 = b0c * qa0, v1 = b1c * qa1;
        float nrm = v0 + v1;
        nrm += __shfl_xor(nrm, 8, 64);
        nrm += __shfl_xor(nrm, 16, 64);
        nrm += __shfl_xor(nrm, 32, 64);
        float invn = 1.0f / nrm;
        size_t pbase = (size_t)Nn * 2 * Gg + (size_t)nu0 * (Cc * Gg);
        stout(out, pbase + i0 * Gg + gW, v0 * invn, isbf);
        stout(out, pbase + i1 * Gg + gW, v1 * invn, isbf);
        if (ii == 0) stout(out, (size_t)nu0 * (2 * Gg) + Gg + gW, logf(nrm), isbf);

        // ---- rotate pipeline ----
        n0 += NW;
        d0 = d1; sd0 = sd1; x0v = x1v;
        d1 = d2; sd1 = sd2; x1v = x2v;
        bA0 = bB0; bA1 = bB1; bA2 = bB2; bA3 = bB3;
        b0c = b0n; b1c = b1n;
    }
}

// ---------------------------------------------------------------------------
extern "C" void kernel_launch(void* const* d_in, const int* in_sizes, int n_in,
                              void* d_out, int out_size, void* d_ws, size_t ws_size,
                              hipStream_t stream) {
    const int* x  = (const int*)d_in[0];
    const int* ei = (const int*)d_in[1];
    const void* B0 = d_in[2];
    const void* Pi = d_in[3];
    const void* B1 = d_in[4];
    const void* Q  = d_in[5];

    // ws: flag(128) | smB1(4096) | smQg(2048) | post0 ((Nn+1)*128 bf16)
    //   | deg (Nn) | sorted_dst (Nn*CAP) | segcnt (NBK*P1B) | segbuf (NBK*P1B*SEGCAP)
    float* ws = (float*)d_ws;
    int*   flag   = (int*)ws;                     // 1 (padded to 128)
    float* smB1ws = ws + 128;                     // 4096 [i][m][g]
    float* smQgws = smB1ws + 4096;                // 2048 [g][i][l]
    unsigned short* post0 = (unsigned short*)(smQgws + 2048);  // (Nn+1)*128 bf16 [n][g][c]
    int* deg        = (int*)(post0 + (size_t)(Nn + 1) * 128);  // Nn ints
    int* sorted_dst = deg + Nn;                                // Nn*CAP ints
    int* segcnt     = sorted_dst + (size_t)Nn * CAP;           // NBK*P1B ints (128K)
    unsigned* segbuf = (unsigned*)(segcnt + NBK * P1B);        // NBK*P1B*SEGCAP u32 (8MB)

    bucket_layer0<<<P1B + L0B + 1, 256, 0, stream>>>(
        ei, x, B0, Pi, B1, Q, segbuf, segcnt, post0, smB1ws, smQgws, flag, d_out);

    place_edges<<<NBK, 256, 0, stream>>>(segbuf, segcnt, deg, sorted_dst);

    aggr_layer1<<<NAB, 256, 0, stream>>>(
        deg, sorted_dst, post0, x, smB1ws, smQgws, flag, d_out);
}